// Round 2
// baseline (706.130 us; speedup 1.0000x reference)
//
#include <hip/hip_runtime.h>
#include <stdint.h>

#define Bn 256
#define Nn 512
#define Fn 256
#define Hn 256
#define NSn 5
#define EPS 1e-5f
#define LSTR2 72  // LDS row stride in ushorts for BK=64 tiles (144B: 16B-aligned,
                  // bank walk 4*row mod 32 -> worst 2-way on b128 frag reads = free)

typedef __attribute__((ext_vector_type(8))) short bf16x8;
typedef __attribute__((ext_vector_type(4))) float f32x4;

__device__ __forceinline__ unsigned short f2bf(float x) {
  unsigned int u = __float_as_uint(x);
  u += 0x7FFFu + ((u >> 16) & 1u);          // RTNE
  return (unsigned short)(u >> 16);
}
// Packed f32x2 -> bf16x2. gfx950 has v_cvt_pk_bf16_f32 (1 instr); fall back
// to the proven manual RTNE if the builtin is absent. Rounding-mode deltas are
// selection-safe: selection is guarded by top-4 + exact fp64 re-check.
__device__ __forceinline__ unsigned int pack2bf(float a, float b) {
#if __has_builtin(__builtin_amdgcn_cvt_pk_bf16_f32)
  auto r = __builtin_amdgcn_cvt_pk_bf16_f32(a, b);
  unsigned int u;
  __builtin_memcpy(&u, &r, 4);
  return u;
#else
  return (unsigned int)f2bf(a) | ((unsigned int)f2bf(b) << 16);
#endif
}

// ---------------------------------------------------------------------------
// k0: W0T[h][f] = bf16(W0[f][h]) via LDS tile transpose (coalesced R/W).
// ---------------------------------------------------------------------------
__global__ __launch_bounds__(256) void k0_prep(const float* __restrict__ W0,
                                               unsigned short* __restrict__ W0T) {
  __shared__ float tile[64][68];
  const int tid = (int)threadIdx.x;
  const int ti = blockIdx.x >> 2, tj = blockIdx.x & 3;   // f-tile, h-tile
#pragma unroll
  for (int q = 0; q < 4; ++q) {
    int s = tid + 256 * q;
    int r = s >> 4, c4 = s & 15;
    *(float4*)&tile[r][c4 * 4] =
        *(const float4*)(W0 + (size_t)(ti * 64 + r) * Hn + tj * 64 + c4 * 4);
  }
  __syncthreads();
#pragma unroll
  for (int q = 0; q < 4; ++q) {
    int s = tid + 256 * q;
    int hh = s >> 4, fq = s & 15;
    int ff = fq * 4;
    float t0 = tile[ff + 0][hh], t1 = tile[ff + 1][hh];
    float t2 = tile[ff + 2][hh], t3 = tile[ff + 3][hh];
    *(uint2*)(W0T + (size_t)(tj * 64 + hh) * Fn + ti * 64 + ff) =
        make_uint2(pack2bf(t0, t1), pack2bf(t2, t3));
  }
}

// ---------------------------------------------------------------------------
// k1: supT[b][h][node] = bf16((features@W0)[node][h]) via MFMA bf16.
// 128x256 tile, 512 threads = 8 waves (2 row-halves x 4 col-quarters),
// wave tile 64x64 = acc[4][4] (proven mapping). K=256, BK=64: halves the
// barrier-drain count vs BK=32 (4 iters instead of 8) — the per-iteration
// fixed overhead (2 barriers + full waitcnt drain + loop bookkeeping) was
// the remaining attackable cost; per-element VALU is unchanged.
// LDS 55.3 KB -> still 2 blocks/CU. No reg prefetch (measured Delta=0).
// ---------------------------------------------------------------------------
__global__ __launch_bounds__(512) void k1_support(
    const float* __restrict__ feat, const unsigned short* __restrict__ W0T,
    unsigned short* __restrict__ supT)
{
  __shared__ __align__(16) unsigned short As[128 * LSTR2];   // 18.4 KB
  __shared__ __align__(16) unsigned short Bs[256 * LSTR2];   // 36.9 KB
  const int tid = (int)threadIdx.x;
  const int wv = tid >> 6, lane = tid & 63;
  const int wr = wv >> 2, wc = wv & 3;
  const int m0 = blockIdx.x * 128;
  f32x4 acc[4][4];
  const f32x4 z4 = {0.f, 0.f, 0.f, 0.f};
#pragma unroll
  for (int i = 0; i < 4; ++i)
#pragma unroll
    for (int j = 0; j < 4; ++j) acc[i][j] = z4;

  // A staging: 128 rows x 64 cols, 16 elems/thread (4x float4 -> 2x uint4)
  const int ar = tid >> 2, acg = (tid & 3) * 16;
  // B staging: 256 rows x 64 cols, 32 elems/thread (4x uint4 copy)
  const int br = tid >> 1, bcg = (tid & 1) * 32;
  const float* ap = feat + (size_t)(m0 + ar) * Fn + acg;
  const unsigned short* bp = W0T + (size_t)br * Fn + bcg;
  unsigned short* const asw = &As[ar * LSTR2 + acg];
  unsigned short* const bsw = &Bs[br * LSTR2 + bcg];

  for (int k0 = 0; k0 < Fn; k0 += 64) {
    float4 v0 = *(const float4*)(ap + k0);
    float4 v1 = *(const float4*)(ap + k0 + 4);
    float4 v2 = *(const float4*)(ap + k0 + 8);
    float4 v3 = *(const float4*)(ap + k0 + 12);
    *(uint4*)asw = make_uint4(pack2bf(v0.x, v0.y), pack2bf(v0.z, v0.w),
                              pack2bf(v1.x, v1.y), pack2bf(v1.z, v1.w));
    *(uint4*)(asw + 8) = make_uint4(pack2bf(v2.x, v2.y), pack2bf(v2.z, v2.w),
                                    pack2bf(v3.x, v3.y), pack2bf(v3.z, v3.w));
    *(uint4*)(bsw)      = *(const uint4*)(bp + k0);
    *(uint4*)(bsw + 8)  = *(const uint4*)(bp + k0 + 8);
    *(uint4*)(bsw + 16) = *(const uint4*)(bp + k0 + 16);
    *(uint4*)(bsw + 24) = *(const uint4*)(bp + k0 + 24);
    __syncthreads();
#pragma unroll
    for (int ks = 0; ks < 2; ++ks) {
      bf16x8 af[4], bfr[4];
#pragma unroll
      for (int i = 0; i < 4; ++i) {
        af[i]  = *(const bf16x8*)&As[(wr * 64 + i * 16 + (lane & 15)) * LSTR2 + ks * 32 + (lane >> 4) * 8];
        bfr[i] = *(const bf16x8*)&Bs[(wc * 64 + i * 16 + (lane & 15)) * LSTR2 + ks * 32 + (lane >> 4) * 8];
      }
#pragma unroll
      for (int mi = 0; mi < 4; ++mi)
#pragma unroll
        for (int nt = 0; nt < 4; ++nt)
          acc[mi][nt] = __builtin_amdgcn_mfma_f32_16x16x32_bf16(af[mi], bfr[nt], acc[mi][nt], 0, 0, 0);
    }
    __syncthreads();
  }
  const int b = m0 >> 9;
  const int nodebase = (m0 & 511) + wr * 64;
  unsigned short* outb = supT + ((size_t)b << 17);
#pragma unroll
  for (int mi = 0; mi < 4; ++mi)
#pragma unroll
    for (int nt = 0; nt < 4; ++nt) {
      int h = wc * 64 + nt * 16 + (lane & 15);
      int node = nodebase + mi * 16 + (lane >> 4) * 4;
      *(uint2*)(outb + (size_t)h * Nn + node) =
          make_uint2(pack2bf(acc[mi][nt][0], acc[mi][nt][1]),
                     pack2bf(acc[mi][nt][2], acc[mi][nt][3]));
    }
}

// ---------------------------------------------------------------------------
// k2: per batch, scores[node] = sum_h relu(LN0(adj@sup + b0)) via MFMA bf16.
// 128x256 tile, 512 threads / 8 waves; fused LN epilogue; x never stored.
// BK=64: 8 barrier-pairs instead of 16 (same rationale as k1).
// XCD-chunked swizzle keeps the 4 blocks of a batch on one XCD's L2 (supb
// 256 KB fetched once per XCD instead of 4x).
// ---------------------------------------------------------------------------
__global__ __launch_bounds__(512) void k2_scores(
    const float* __restrict__ adj, const unsigned short* __restrict__ supT,
    const float* __restrict__ b0, const float* __restrict__ g0,
    const float* __restrict__ be0, float* __restrict__ scores)
{
  __shared__ __align__(16) unsigned short As[128 * LSTR2];
  __shared__ __align__(16) unsigned short Bs[256 * LSTR2];
  const int tid = (int)threadIdx.x;
  const int wv = tid >> 6, lane = tid & 63;
  const int wr = wv >> 2, wc = wv & 3;
  const int bid = (int)blockIdx.x;
  const int swz = (bid & 7) * 128 + (bid >> 3);   // bijective: 1024 % 8 == 0
  const int b = swz >> 2;
  const int m0 = (swz & 3) * 128;
  const float* adjb = adj + ((size_t)b << 18);
  const unsigned short* supb = supT + ((size_t)b << 17);
  f32x4 acc[4][4];
  const f32x4 z4 = {0.f, 0.f, 0.f, 0.f};
#pragma unroll
  for (int i = 0; i < 4; ++i)
#pragma unroll
    for (int j = 0; j < 4; ++j) acc[i][j] = z4;

  const int ar = tid >> 2, acg = (tid & 3) * 16;
  const int br = tid >> 1, bcg = (tid & 1) * 32;
  const float* ap = adjb + (size_t)(m0 + ar) * Nn + acg;
  const unsigned short* bp = supb + (size_t)br * Nn + bcg;
  unsigned short* const asw = &As[ar * LSTR2 + acg];
  unsigned short* const bsw = &Bs[br * LSTR2 + bcg];

  for (int k0 = 0; k0 < Nn; k0 += 64) {
    float4 v0 = *(const float4*)(ap + k0);
    float4 v1 = *(const float4*)(ap + k0 + 4);
    float4 v2 = *(const float4*)(ap + k0 + 8);
    float4 v3 = *(const float4*)(ap + k0 + 12);
    *(uint4*)asw = make_uint4(pack2bf(v0.x, v0.y), pack2bf(v0.z, v0.w),
                              pack2bf(v1.x, v1.y), pack2bf(v1.z, v1.w));
    *(uint4*)(asw + 8) = make_uint4(pack2bf(v2.x, v2.y), pack2bf(v2.z, v2.w),
                                    pack2bf(v3.x, v3.y), pack2bf(v3.z, v3.w));
    *(uint4*)(bsw)      = *(const uint4*)(bp + k0);
    *(uint4*)(bsw + 8)  = *(const uint4*)(bp + k0 + 8);
    *(uint4*)(bsw + 16) = *(const uint4*)(bp + k0 + 16);
    *(uint4*)(bsw + 24) = *(const uint4*)(bp + k0 + 24);
    __syncthreads();
#pragma unroll
    for (int ks = 0; ks < 2; ++ks) {
      bf16x8 af[4], bfr[4];
#pragma unroll
      for (int i = 0; i < 4; ++i) {
        af[i]  = *(const bf16x8*)&As[(wr * 64 + i * 16 + (lane & 15)) * LSTR2 + ks * 32 + (lane >> 4) * 8];
        bfr[i] = *(const bf16x8*)&Bs[(wc * 64 + i * 16 + (lane & 15)) * LSTR2 + ks * 32 + (lane >> 4) * 8];
      }
#pragma unroll
      for (int mi = 0; mi < 4; ++mi)
#pragma unroll
        for (int nt = 0; nt < 4; ++nt)
          acc[mi][nt] = __builtin_amdgcn_mfma_f32_16x16x32_bf16(af[mi], bfr[nt], acc[mi][nt], 0, 0, 0);
    }
    __syncthreads();
  }

  // Epilogue. red in As space: s1[128*4] | s2 at +512 | sc at +1024 (floats)
  float* red = (float*)As;
  float b0v[4], g0v[4], be0v[4];
#pragma unroll
  for (int nt = 0; nt < 4; ++nt) {
    int col = wc * 64 + nt * 16 + (lane & 15);
    b0v[nt] = b0[col]; g0v[nt] = g0[col]; be0v[nt] = be0[col];
  }
#pragma unroll
  for (int mi = 0; mi < 4; ++mi)
#pragma unroll
    for (int rg = 0; rg < 4; ++rg) {
      float s1 = 0.f, s2 = 0.f;
#pragma unroll
      for (int nt = 0; nt < 4; ++nt) {
        float x = acc[mi][nt][rg] + b0v[nt];
        s1 += x; s2 += x * x;
      }
#pragma unroll
      for (int off = 8; off >= 1; off >>= 1) {
        s1 += __shfl_xor(s1, off);
        s2 += __shfl_xor(s2, off);
      }
      if ((lane & 15) == 0) {
        int row = wr * 64 + mi * 16 + (lane >> 4) * 4 + rg;
        red[row * 4 + wc] = s1;
        red[512 + row * 4 + wc] = s2;
      }
    }
  __syncthreads();
#pragma unroll
  for (int mi = 0; mi < 4; ++mi)
#pragma unroll
    for (int rg = 0; rg < 4; ++rg) {
      int row = wr * 64 + mi * 16 + (lane >> 4) * 4 + rg;
      float s1 = red[row*4] + red[row*4+1] + red[row*4+2] + red[row*4+3];
      float s2 = red[512+row*4] + red[512+row*4+1] + red[512+row*4+2] + red[512+row*4+3];
      float m = s1 * (1.0f / Hn);
      float var = s2 * (1.0f / Hn) - m * m;
      float rstd = 1.0f / sqrtf(var + EPS);
      float sc = 0.f;
#pragma unroll
      for (int nt = 0; nt < 4; ++nt) {
        float x = acc[mi][nt][rg] + b0v[nt];
        float zz = (x - m) * rstd * g0v[nt] + be0v[nt];
        sc += fmaxf(zz, 0.f);
      }
#pragma unroll
      for (int off = 8; off >= 1; off >>= 1) sc += __shfl_xor(sc, off);
      if ((lane & 15) == 0) red[1024 + row * 4 + wc] = sc;
    }
  __syncthreads();
  if (tid < 128) {
    float s = red[1024+tid*4] + red[1024+tid*4+1] + red[1024+tid*4+2] + red[1024+tid*4+3];
    scores[b * Nn + m0 + tid] = s;
  }
}

// ---------------------------------------------------------------------------
// k3a: one block/batch. Top-4 per stage from bf16 scores (iterative argmax,
// jnp tie rule = smallest index). Stages are INDEPENDENT (sid partitions the
// nodes), so wave w handles stages {w, w+4}: wave-local shfl argmax, zero
// intra-round barriers. Cross-wave LDS writes are benign: sid only ever
// transitions s -> -1, which matches no other wave's stage predicate.
// ---------------------------------------------------------------------------
__global__ __launch_bounds__(256) void k3a_select(
    const float* __restrict__ scores, const int* __restrict__ sid,
    int* __restrict__ candbuf)
{
  __shared__ float sc_s[Nn];
  __shared__ int sid_s[Nn];
  __shared__ int cand[20], candv[20];
  const int tid = (int)threadIdx.x;
  const int b = blockIdx.x;

  for (int i = tid; i < Nn; i += 256) {
    sc_s[i] = scores[b * Nn + i];
    sid_s[i] = sid[b * Nn + i];
  }
  __syncthreads();

  const int wv = tid >> 6, lane = tid & 63;
  for (int s = wv; s < NSn; s += 4) {
    for (int j = 0; j < 4; ++j) {
      unsigned long long best = 0ull;
      for (int i = lane; i < Nn; i += 64)
        if (sid_s[i] == s) {
          unsigned int fb = __float_as_uint(sc_s[i]);
          fb = (fb & 0x80000000u) ? ~fb : (fb | 0x80000000u);
          unsigned long long key = ((unsigned long long)fb << 32) |
                                   (unsigned long long)(unsigned)(Nn - 1 - i);
          if (key > best) best = key;
        }
#pragma unroll
      for (int off = 32; off >= 1; off >>= 1) {
        unsigned long long o = __shfl_xor(best, off);
        if (o > best) best = o;
      }
      int c = s * 4 + j;
      if (best != 0ull) {
        int node = Nn - 1 - (int)(best & 0xFFFFFFFFull);
        sid_s[node] = -1;                 // all lanes, same value: benign
        if (lane == 0) { cand[c] = node; candv[c] = 1; }
      } else if (lane == 0) {
        cand[c] = 0; candv[c] = 0;
      }
    }
  }
  __syncthreads();

  if (tid < 20) {
    candbuf[b * 40 + tid] = cand[tid];
    candbuf[b * 40 + 20 + tid] = candv[tid];
  }
}

// ---------------------------------------------------------------------------
// k3b: grid (256 batches x 4 n-chunks). Stage the 20 candidate adj-row slices
// as fp64 in LDS (converted ONCE), then fp64 partials of
// t_c = adj_row_c @ feat[b] over this chunk. FMA operand order preserved
// exactly -> px bit-identical. feat read exactly once across the grid.
// ---------------------------------------------------------------------------
__global__ __launch_bounds__(256) void k3b_part(
    const float* __restrict__ adj, const float* __restrict__ feat,
    const int* __restrict__ candbuf, double* __restrict__ px)
{
  __shared__ __align__(16) double adjs[20][128];
  __shared__ int cand[20];
  const int tid = (int)threadIdx.x;
  const int b = blockIdx.x >> 2, ch = blockIdx.x & 3;

  if (tid < 20) cand[tid] = candbuf[b * 40 + tid];
  __syncthreads();

  const float* adjb = adj + ((size_t)b << 18);
  for (int idx = tid; idx < 20 * 128; idx += 256) {
    int c = idx >> 7, n = idx & 127;
    adjs[c][n] = (double)adjb[((size_t)cand[c] << 9) + ch * 128 + n];
  }
  __syncthreads();

  double t[20];
#pragma unroll
  for (int c = 0; c < 20; ++c) t[c] = 0.0;
  const float* fp = feat + ((size_t)b << 17) + (((size_t)ch * 128) << 8) + tid;
  for (int n0 = 0; n0 < 128; n0 += 4) {
    double d0 = (double)fp[(size_t)(n0 + 0) << 8];
    double d1 = (double)fp[(size_t)(n0 + 1) << 8];
    double d2 = (double)fp[(size_t)(n0 + 2) << 8];
    double d3 = (double)fp[(size_t)(n0 + 3) << 8];
#pragma unroll
    for (int c = 0; c < 20; ++c) {
      const double* av = &adjs[c][n0];
      t[c] += av[0] * d0 + av[1] * d1 + av[2] * d2 + av[3] * d3;
    }
  }
  double* pxb = px + ((size_t)(b * 4 + ch) * 20) * 256 + tid;
#pragma unroll
  for (int c = 0; c < 20; ++c) pxb[(size_t)c * 256] = t[c];
}

// ---------------------------------------------------------------------------
__device__ __forceinline__ float brs(float v) {
  __shared__ float sb[4];
#pragma unroll
  for (int off = 32; off >= 1; off >>= 1) v += __shfl_xor(v, off);
  __syncthreads();
  if ((threadIdx.x & 63) == 0) sb[threadIdx.x >> 6] = v;
  __syncthreads();
  return sb[0] + sb[1] + sb[2] + sb[3];
}

// ---------------------------------------------------------------------------
// k3c: one block/batch. Reduce t partials, x = t @ W0 (fp32), exact LN0
// scores per candidate (per-wave parallel), winner per stage, then the tail.
// ---------------------------------------------------------------------------
__global__ __launch_bounds__(256) void k3c_final(
    const double* __restrict__ px, const int* __restrict__ candbuf,
    const float* __restrict__ W0, const float* __restrict__ b0,
    const float* __restrict__ b1, const float* __restrict__ W2,
    const float* __restrict__ b2, const float* __restrict__ g0,
    const float* __restrict__ be0, const float* __restrict__ g1,
    const float* __restrict__ be1, const float* __restrict__ g2,
    const float* __restrict__ be2, const float* __restrict__ fcW,
    const float* __restrict__ fcb, float* __restrict__ out)
{
  __shared__ __align__(16) float tfT[Fn * 20];   // [f][c]
  __shared__ float xb[20][Hn];
  __shared__ float b0s[Hn], g0s[Hn], be0s[Hn];
  __shared__ float cm[20], cr[20], csc[20];
  __shared__ int candL[20], candvL[20], winslot[NSn];
  __shared__ float xs[Hn];
  const int tid = (int)threadIdx.x;
  const int b = blockIdx.x;

  if (tid < 20) {
    candL[tid] = candbuf[b * 40 + tid];
    candvL[tid] = candbuf[b * 40 + 20 + tid];
  }
  b0s[tid] = b0[tid]; g0s[tid] = g0[tid]; be0s[tid] = be0[tid];
  {
    const double* pxb = px + ((size_t)b * 4 * 20) * 256 + tid;
#pragma unroll
    for (int c = 0; c < 20; ++c) {
      double t = pxb[(size_t)c * 256] + pxb[(size_t)(20 + c) * 256] +
                 pxb[(size_t)(40 + c) * 256] + pxb[(size_t)(60 + c) * 256];
      tfT[tid * 20 + c] = (float)t;
    }
  }
  __syncthreads();

  {
    float xc[20];
#pragma unroll
    for (int c = 0; c < 20; ++c) xc[c] = 0.f;
    for (int f = 0; f < Fn; ++f) {
      float w = W0[(size_t)f * Hn + tid];
      const float* tp = &tfT[f * 20];
      float4 t0 = *(const float4*)(tp);
      float4 t1 = *(const float4*)(tp + 4);
      float4 t2 = *(const float4*)(tp + 8);
      float4 t3 = *(const float4*)(tp + 12);
      float4 t4 = *(const float4*)(tp + 16);
      xc[0] = fmaf(t0.x, w, xc[0]);   xc[1] = fmaf(t0.y, w, xc[1]);
      xc[2] = fmaf(t0.z, w, xc[2]);   xc[3] = fmaf(t0.w, w, xc[3]);
      xc[4] = fmaf(t1.x, w, xc[4]);   xc[5] = fmaf(t1.y, w, xc[5]);
      xc[6] = fmaf(t1.z, w, xc[6]);   xc[7] = fmaf(t1.w, w, xc[7]);
      xc[8] = fmaf(t2.x, w, xc[8]);   xc[9] = fmaf(t2.y, w, xc[9]);
      xc[10] = fmaf(t2.z, w, xc[10]); xc[11] = fmaf(t2.w, w, xc[11]);
      xc[12] = fmaf(t3.x, w, xc[12]); xc[13] = fmaf(t3.y, w, xc[13]);
      xc[14] = fmaf(t3.z, w, xc[14]); xc[15] = fmaf(t3.w, w, xc[15]);
      xc[16] = fmaf(t4.x, w, xc[16]); xc[17] = fmaf(t4.y, w, xc[17]);
      xc[18] = fmaf(t4.z, w, xc[18]); xc[19] = fmaf(t4.w, w, xc[19]);
    }
#pragma unroll
    for (int c = 0; c < 20; ++c) xb[c][tid] = xc[c];
  }
  __syncthreads();

  {
    const int wv = tid >> 6, lane = tid & 63;
    for (int c = wv; c < 20; c += 4) {
      float v0 = xb[c][lane] + b0s[lane];
      float v1 = xb[c][lane + 64] + b0s[lane + 64];
      float v2 = xb[c][lane + 128] + b0s[lane + 128];
      float v3 = xb[c][lane + 192] + b0s[lane + 192];
      float s = v0 + v1 + v2 + v3;
#pragma unroll
      for (int off = 32; off >= 1; off >>= 1) s += __shfl_xor(s, off);
      float m = s * (1.0f / Hn);
      float d0 = v0 - m, d1 = v1 - m, d2 = v2 - m, d3 = v3 - m;
      float s2 = d0 * d0 + d1 * d1 + d2 * d2 + d3 * d3;
#pragma unroll
      for (int off = 32; off >= 1; off >>= 1) s2 += __shfl_xor(s2, off);
      float rstd = 1.0f / sqrtf(s2 * (1.0f / Hn) + EPS);
      float sc = fmaxf(d0 * rstd * g0s[lane] + be0s[lane], 0.f) +
                 fmaxf(d1 * rstd * g0s[lane + 64] + be0s[lane + 64], 0.f) +
                 fmaxf(d2 * rstd * g0s[lane + 128] + be0s[lane + 128], 0.f) +
                 fmaxf(d3 * rstd * g0s[lane + 192] + be0s[lane + 192], 0.f);
#pragma unroll
      for (int off = 32; off >= 1; off >>= 1) sc += __shfl_xor(sc, off);
      if (lane == 0) { cm[c] = m; cr[c] = rstd; csc[c] = sc; }
    }
  }
  __syncthreads();

  if (tid == 0) {
#pragma unroll
    for (int s = 0; s < NSn; ++s) {
      int wsl = s * 4;
      float bestv = 0.f; int bestn = 0; bool any = false;
      for (int j = 0; j < 4; ++j) {
        int c = s * 4 + j;
        if (!candvL[c]) continue;
        float v = csc[c]; int node = candL[c];
        if (!any || v > bestv || (v == bestv && node < bestn)) {
          any = true; bestv = v; bestn = node; wsl = c;
        }
      }
      winslot[s] = wsl;
    }
  }
  __syncthreads();

  const float b0t = b0s[tid], g0t = g0s[tid], be0t = be0s[tid];
  const float b1t = b1[tid], g1t = g1[tid], be1t = be1[tid];
  float xsum = 0.f;
  for (int s = 0; s < NSn; ++s) {
    int c = winslot[s];
    float xv = xb[c][tid] + b0t;
    float z0 = (xv - cm[c]) * cr[c] * g0t + be0t;
    float o = fmaxf(z0, 0.f) + b1t;
    float m1 = brs(o) * (1.0f / Hn);
    float d1 = o - m1;
    float v1 = brs(d1 * d1) * (1.0f / Hn);
    float z1 = d1 * (1.0f / sqrtf(v1 + EPS)) * g1t + be1t;
    xsum += fmaxf(z1, 0.f);
  }
  xs[tid] = xsum;
  __syncthreads();
  float y = 0.f;
  for (int h = 0; h < Hn; h += 4) {
    float4 xv4 = *(const float4*)&xs[h];
    y = fmaf(xv4.x, W2[(size_t)h * Hn + tid], y);
    y = fmaf(xv4.y, W2[(size_t)(h + 1) * Hn + tid], y);
    y = fmaf(xv4.z, W2[(size_t)(h + 2) * Hn + tid], y);
    y = fmaf(xv4.w, W2[(size_t)(h + 3) * Hn + tid], y);
  }
  y += b2[tid];
  float m2 = brs(y) * (1.0f / Hn);
  float d2 = y - m2;
  float v2 = brs(d2 * d2) * (1.0f / Hn);
  float z2 = d2 * (1.0f / sqrtf(v2 + EPS)) * g2[tid] + be2[tid];
  float p = fmaxf(z2, 0.f) * fcW[tid];
  float tot = brs(p);
  if (tid == 0) out[b] = tot + fcb[0];
}

// ---------------------------------------------------------------------------
extern "C" void kernel_launch(void* const* d_in, const int* in_sizes, int n_in,
                              void* d_out, int out_size, void* d_ws, size_t ws_size,
                              hipStream_t stream)
{
  (void)in_sizes; (void)n_in; (void)out_size; (void)ws_size;
  const float* adj  = (const float*)d_in[0];
  const float* feat = (const float*)d_in[1];
  const int*   sid  = (const int*)d_in[2];
  const float* W0   = (const float*)d_in[3];
  const float* b0   = (const float*)d_in[4];
  const float* b1   = (const float*)d_in[5];
  const float* W2   = (const float*)d_in[6];
  const float* b2   = (const float*)d_in[7];
  const float* g0   = (const float*)d_in[8];
  const float* be0  = (const float*)d_in[9];
  const float* g1   = (const float*)d_in[10];
  const float* be1  = (const float*)d_in[11];
  const float* g2   = (const float*)d_in[12];
  const float* be2  = (const float*)d_in[13];
  const float* fcW  = (const float*)d_in[14];
  const float* fcb  = (const float*)d_in[15];
  float* out = (float*)d_out;

  // ws: supT bf16 [B][H][N] 67,108,864 | W0T bf16 131,072 | scores f32 524,288
  //     | candbuf int 40,960 | px f64 41,943,040
  unsigned short* supT = (unsigned short*)d_ws;
  unsigned short* W0T  = (unsigned short*)((char*)d_ws + 67108864);
  float* scores        = (float*)((char*)d_ws + 67239936);
  int* candbuf         = (int*)((char*)d_ws + 67764224);
  double* px           = (double*)((char*)d_ws + 67805184);

  k0_prep<<<dim3(16), dim3(256), 0, stream>>>(W0, W0T);
  k1_support<<<dim3(1024), dim3(512), 0, stream>>>(feat, W0T, supT);
  k2_scores<<<dim3(1024), dim3(512), 0, stream>>>(adj, supT, b0, g0, be0, scores);
  k3a_select<<<dim3(256), dim3(256), 0, stream>>>(scores, sid, candbuf);
  k3b_part<<<dim3(1024), dim3(256), 0, stream>>>(adj, feat, candbuf, px);
  k3c_final<<<dim3(256), dim3(256), 0, stream>>>(px, candbuf,
      W0, b0, b1, W2, b2, g0, be0, g1, be1, g2, be2, fcW, fcb, out);
}

// Round 3
// 695.571 us; speedup vs baseline: 1.0152x; 1.0152x over previous
//
#include <hip/hip_runtime.h>
#include <stdint.h>

#define Bn 256
#define Nn 512
#define Fn 256
#define Hn 256
#define NSn 5
#define EPS 1e-5f
#define LSTR 56   // LDS row stride in ushorts (112B: 16B-aligned, 2-lane bank groups)

typedef __attribute__((ext_vector_type(8))) short bf16x8;
typedef __attribute__((ext_vector_type(4))) float f32x4;

__device__ __forceinline__ unsigned short f2bf(float x) {
  unsigned int u = __float_as_uint(x);
  u += 0x7FFFu + ((u >> 16) & 1u);          // RTNE
  return (unsigned short)(u >> 16);
}
// Packed f32x2 -> bf16x2. gfx950 has v_cvt_pk_bf16_f32 (1 instr); fall back
// to the proven manual RTNE if the builtin is absent. Rounding-mode deltas are
// selection-safe: selection is guarded by top-4 + exact fp64 re-check.
__device__ __forceinline__ unsigned int pack2bf(float a, float b) {
#if __has_builtin(__builtin_amdgcn_cvt_pk_bf16_f32)
  auto r = __builtin_amdgcn_cvt_pk_bf16_f32(a, b);
  unsigned int u;
  __builtin_memcpy(&u, &r, 4);
  return u;
#else
  return (unsigned int)f2bf(a) | ((unsigned int)f2bf(b) << 16);
#endif
}

// ---------------------------------------------------------------------------
// k0: W0T[h][f] = bf16(W0[f][h]) via LDS tile transpose (coalesced R/W).
// ---------------------------------------------------------------------------
__global__ __launch_bounds__(256) void k0_prep(const float* __restrict__ W0,
                                               unsigned short* __restrict__ W0T) {
  __shared__ float tile[64][68];
  const int tid = (int)threadIdx.x;
  const int ti = blockIdx.x >> 2, tj = blockIdx.x & 3;   // f-tile, h-tile
#pragma unroll
  for (int q = 0; q < 4; ++q) {
    int s = tid + 256 * q;
    int r = s >> 4, c4 = s & 15;
    *(float4*)&tile[r][c4 * 4] =
        *(const float4*)(W0 + (size_t)(ti * 64 + r) * Hn + tj * 64 + c4 * 4);
  }
  __syncthreads();
#pragma unroll
  for (int q = 0; q < 4; ++q) {
    int s = tid + 256 * q;
    int hh = s >> 4, fq = s & 15;
    int ff = fq * 4;
    float t0 = tile[ff + 0][hh], t1 = tile[ff + 1][hh];
    float t2 = tile[ff + 2][hh], t3 = tile[ff + 3][hh];
    *(uint2*)(W0T + (size_t)(tj * 64 + hh) * Fn + ti * 64 + ff) =
        make_uint2(pack2bf(t0, t1), pack2bf(t2, t3));
  }
}

// ---------------------------------------------------------------------------
// k1: supT[b][h][node] = bf16((features@W0)[node][h]) via MFMA bf16.
// 128x256 tile, 512 threads = 8 waves (2 row-halves x 4 col-quarters),
// wave tile 64x64 = acc[4][4] (proven mapping). K=256, BK=32.
// NOTE (measured): T14 reg-prefetch = null (r1), BK=64 barrier-halving =
// -5us regression (r2). This BK=32 2-barrier loop is the best-measured
// structure for this shape; do not re-add either without fresh evidence.
// ---------------------------------------------------------------------------
__global__ __launch_bounds__(512) void k1_support(
    const float* __restrict__ feat, const unsigned short* __restrict__ W0T,
    unsigned short* __restrict__ supT)
{
  __shared__ __align__(16) unsigned short As[128 * LSTR];
  __shared__ __align__(16) unsigned short Bs[256 * LSTR];
  const int tid = (int)threadIdx.x;
  const int wv = tid >> 6, lane = tid & 63;
  const int wr = wv >> 2, wc = wv & 3;
  const int m0 = blockIdx.x * 128;
  f32x4 acc[4][4];
  const f32x4 z4 = {0.f, 0.f, 0.f, 0.f};
#pragma unroll
  for (int i = 0; i < 4; ++i)
#pragma unroll
    for (int j = 0; j < 4; ++j) acc[i][j] = z4;

  const int ar = tid >> 2, ac = tid & 3;   // A: row 0..127, col-group (8 elems)
  for (int k0 = 0; k0 < Fn; k0 += 32) {
    {
      const float* ap = feat + (size_t)(m0 + ar) * Fn + k0 + ac * 8;
      float4 v0 = *(const float4*)ap;
      float4 v1 = *(const float4*)(ap + 4);
      uint4 pk = make_uint4(pack2bf(v0.x, v0.y), pack2bf(v0.z, v0.w),
                            pack2bf(v1.x, v1.y), pack2bf(v1.z, v1.w));
      *(uint4*)&As[ar * LSTR + ac * 8] = pk;
    }
#pragma unroll
    for (int q = 0; q < 2; ++q) {
      int s = tid + 512 * q;              // 0..1023
      int r = s >> 2, cg = s & 3;         // h-row 0..255
      *(uint4*)&Bs[r * LSTR + cg * 8] =
          *(const uint4*)(W0T + (size_t)r * Fn + k0 + cg * 8);
    }
    __syncthreads();
    bf16x8 af[4], bfr[4];
#pragma unroll
    for (int i = 0; i < 4; ++i) {
      af[i]  = *(const bf16x8*)&As[(wr * 64 + i * 16 + (lane & 15)) * LSTR + (lane >> 4) * 8];
      bfr[i] = *(const bf16x8*)&Bs[(wc * 64 + i * 16 + (lane & 15)) * LSTR + (lane >> 4) * 8];
    }
#pragma unroll
    for (int mi = 0; mi < 4; ++mi)
#pragma unroll
      for (int nt = 0; nt < 4; ++nt)
        acc[mi][nt] = __builtin_amdgcn_mfma_f32_16x16x32_bf16(af[mi], bfr[nt], acc[mi][nt], 0, 0, 0);
    __syncthreads();
  }
  const int b = m0 >> 9;
  const int nodebase = (m0 & 511) + wr * 64;
  unsigned short* outb = supT + ((size_t)b << 17);
#pragma unroll
  for (int mi = 0; mi < 4; ++mi)
#pragma unroll
    for (int nt = 0; nt < 4; ++nt) {
      int h = wc * 64 + nt * 16 + (lane & 15);
      int node = nodebase + mi * 16 + (lane >> 4) * 4;
      *(uint2*)(outb + (size_t)h * Nn + node) =
          make_uint2(pack2bf(acc[mi][nt][0], acc[mi][nt][1]),
                     pack2bf(acc[mi][nt][2], acc[mi][nt][3]));
    }
}

// ---------------------------------------------------------------------------
// k2: per batch, scores[node] = sum_h relu(LN0(adj@sup + b0)) via MFMA bf16.
// 128x256 tile, 512 threads / 8 waves; fused LN epilogue; x never stored.
// BK=32 (best-measured; see k1 note). XCD-chunked swizzle keeps the 4 blocks
// of a batch on one XCD's L2 (supb 256 KB fetched once per XCD, not 4x).
// ---------------------------------------------------------------------------
__global__ __launch_bounds__(512) void k2_scores(
    const float* __restrict__ adj, const unsigned short* __restrict__ supT,
    const float* __restrict__ b0, const float* __restrict__ g0,
    const float* __restrict__ be0, float* __restrict__ scores)
{
  __shared__ __align__(16) unsigned short As[128 * LSTR];
  __shared__ __align__(16) unsigned short Bs[256 * LSTR];
  const int tid = (int)threadIdx.x;
  const int wv = tid >> 6, lane = tid & 63;
  const int wr = wv >> 2, wc = wv & 3;
  const int bid = (int)blockIdx.x;
  const int swz = (bid & 7) * 128 + (bid >> 3);   // bijective: 1024 % 8 == 0
  const int b = swz >> 2;
  const int m0 = (swz & 3) * 128;
  const float* adjb = adj + ((size_t)b << 18);
  const unsigned short* supb = supT + ((size_t)b << 17);
  f32x4 acc[4][4];
  const f32x4 z4 = {0.f, 0.f, 0.f, 0.f};
#pragma unroll
  for (int i = 0; i < 4; ++i)
#pragma unroll
    for (int j = 0; j < 4; ++j) acc[i][j] = z4;

  const int ar = tid >> 2, ac = tid & 3;
  for (int k0 = 0; k0 < Nn; k0 += 32) {
    {
      const float* ap = adjb + (size_t)(m0 + ar) * Nn + k0 + ac * 8;
      float4 v0 = *(const float4*)ap;
      float4 v1 = *(const float4*)(ap + 4);
      uint4 pk = make_uint4(pack2bf(v0.x, v0.y), pack2bf(v0.z, v0.w),
                            pack2bf(v1.x, v1.y), pack2bf(v1.z, v1.w));
      *(uint4*)&As[ar * LSTR + ac * 8] = pk;
    }
#pragma unroll
    for (int q = 0; q < 2; ++q) {
      int s = tid + 512 * q;
      int r = s >> 2, cg = s & 3;         // h-row 0..255
      *(uint4*)&Bs[r * LSTR + cg * 8] =
          *(const uint4*)(supb + (size_t)r * Nn + k0 + cg * 8);
    }
    __syncthreads();
    bf16x8 af[4], bfr[4];
#pragma unroll
    for (int i = 0; i < 4; ++i) {
      af[i]  = *(const bf16x8*)&As[(wr * 64 + i * 16 + (lane & 15)) * LSTR + (lane >> 4) * 8];
      bfr[i] = *(const bf16x8*)&Bs[(wc * 64 + i * 16 + (lane & 15)) * LSTR + (lane >> 4) * 8];
    }
#pragma unroll
    for (int mi = 0; mi < 4; ++mi)
#pragma unroll
      for (int nt = 0; nt < 4; ++nt)
        acc[mi][nt] = __builtin_amdgcn_mfma_f32_16x16x32_bf16(af[mi], bfr[nt], acc[mi][nt], 0, 0, 0);
    __syncthreads();
  }

  // Epilogue. red in As space: s1[128*4] | s2 at +512 | sc at +1024 (floats)
  float* red = (float*)As;
  float b0v[4], g0v[4], be0v[4];
#pragma unroll
  for (int nt = 0; nt < 4; ++nt) {
    int col = wc * 64 + nt * 16 + (lane & 15);
    b0v[nt] = b0[col]; g0v[nt] = g0[col]; be0v[nt] = be0[col];
  }
#pragma unroll
  for (int mi = 0; mi < 4; ++mi)
#pragma unroll
    for (int rg = 0; rg < 4; ++rg) {
      float s1 = 0.f, s2 = 0.f;
#pragma unroll
      for (int nt = 0; nt < 4; ++nt) {
        float x = acc[mi][nt][rg] + b0v[nt];
        s1 += x; s2 += x * x;
      }
#pragma unroll
      for (int off = 8; off >= 1; off >>= 1) {
        s1 += __shfl_xor(s1, off);
        s2 += __shfl_xor(s2, off);
      }
      if ((lane & 15) == 0) {
        int row = wr * 64 + mi * 16 + (lane >> 4) * 4 + rg;
        red[row * 4 + wc] = s1;
        red[512 + row * 4 + wc] = s2;
      }
    }
  __syncthreads();
#pragma unroll
  for (int mi = 0; mi < 4; ++mi)
#pragma unroll
    for (int rg = 0; rg < 4; ++rg) {
      int row = wr * 64 + mi * 16 + (lane >> 4) * 4 + rg;
      float s1 = red[row*4] + red[row*4+1] + red[row*4+2] + red[row*4+3];
      float s2 = red[512+row*4] + red[512+row*4+1] + red[512+row*4+2] + red[512+row*4+3];
      float m = s1 * (1.0f / Hn);
      float var = s2 * (1.0f / Hn) - m * m;
      float rstd = 1.0f / sqrtf(var + EPS);
      float sc = 0.f;
#pragma unroll
      for (int nt = 0; nt < 4; ++nt) {
        float x = acc[mi][nt][rg] + b0v[nt];
        float zz = (x - m) * rstd * g0v[nt] + be0v[nt];
        sc += fmaxf(zz, 0.f);
      }
#pragma unroll
      for (int off = 8; off >= 1; off >>= 1) sc += __shfl_xor(sc, off);
      if ((lane & 15) == 0) red[1024 + row * 4 + wc] = sc;
    }
  __syncthreads();
  if (tid < 128) {
    float s = red[1024+tid*4] + red[1024+tid*4+1] + red[1024+tid*4+2] + red[1024+tid*4+3];
    scores[b * Nn + m0 + tid] = s;
  }
}

// ---------------------------------------------------------------------------
// k3a: one block/batch. Top-4 per stage from bf16 scores (iterative argmax,
// jnp tie rule = smallest index). Stages are INDEPENDENT (sid partitions the
// nodes), so wave w handles stages {w, w+4}: wave-local shfl argmax, zero
// intra-round barriers. Cross-wave LDS writes are benign: sid only ever
// transitions s -> -1, which matches no other wave's stage predicate.
// ---------------------------------------------------------------------------
__global__ __launch_bounds__(256) void k3a_select(
    const float* __restrict__ scores, const int* __restrict__ sid,
    int* __restrict__ candbuf)
{
  __shared__ float sc_s[Nn];
  __shared__ int sid_s[Nn];
  __shared__ int cand[20], candv[20];
  const int tid = (int)threadIdx.x;
  const int b = blockIdx.x;

  for (int i = tid; i < Nn; i += 256) {
    sc_s[i] = scores[b * Nn + i];
    sid_s[i] = sid[b * Nn + i];
  }
  __syncthreads();

  const int wv = tid >> 6, lane = tid & 63;
  for (int s = wv; s < NSn; s += 4) {
    for (int j = 0; j < 4; ++j) {
      unsigned long long best = 0ull;
      for (int i = lane; i < Nn; i += 64)
        if (sid_s[i] == s) {
          unsigned int fb = __float_as_uint(sc_s[i]);
          fb = (fb & 0x80000000u) ? ~fb : (fb | 0x80000000u);
          unsigned long long key = ((unsigned long long)fb << 32) |
                                   (unsigned long long)(unsigned)(Nn - 1 - i);
          if (key > best) best = key;
        }
#pragma unroll
      for (int off = 32; off >= 1; off >>= 1) {
        unsigned long long o = __shfl_xor(best, off);
        if (o > best) best = o;
      }
      int c = s * 4 + j;
      if (best != 0ull) {
        int node = Nn - 1 - (int)(best & 0xFFFFFFFFull);
        sid_s[node] = -1;                 // all lanes, same value: benign
        if (lane == 0) { cand[c] = node; candv[c] = 1; }
      } else if (lane == 0) {
        cand[c] = 0; candv[c] = 0;
      }
    }
  }
  __syncthreads();

  if (tid < 20) {
    candbuf[b * 40 + tid] = cand[tid];
    candbuf[b * 40 + 20 + tid] = candv[tid];
  }
}

// ---------------------------------------------------------------------------
// k3b: grid (256 batches x 4 n-chunks). Stage the 20 candidate adj-row slices
// as fp64 in LDS (converted ONCE), then fp64 partials of
// t_c = adj_row_c @ feat[b] over this chunk. FMA operand order preserved
// exactly -> px bit-identical. feat read exactly once across the grid.
// 1024 blocks = 4/CU keeps enough loads in flight (don't consolidate chunks:
// 256 blocks would drop TLP 4x on an HBM-streaming kernel).
// ---------------------------------------------------------------------------
__global__ __launch_bounds__(256) void k3b_part(
    const float* __restrict__ adj, const float* __restrict__ feat,
    const int* __restrict__ candbuf, double* __restrict__ px)
{
  __shared__ __align__(16) double adjs[20][128];
  __shared__ int cand[20];
  const int tid = (int)threadIdx.x;
  const int b = blockIdx.x >> 2, ch = blockIdx.x & 3;

  if (tid < 20) cand[tid] = candbuf[b * 40 + tid];
  __syncthreads();

  const float* adjb = adj + ((size_t)b << 18);
  for (int idx = tid; idx < 20 * 128; idx += 256) {
    int c = idx >> 7, n = idx & 127;
    adjs[c][n] = (double)adjb[((size_t)cand[c] << 9) + ch * 128 + n];
  }
  __syncthreads();

  double t[20];
#pragma unroll
  for (int c = 0; c < 20; ++c) t[c] = 0.0;
  const float* fp = feat + ((size_t)b << 17) + (((size_t)ch * 128) << 8) + tid;
  for (int n0 = 0; n0 < 128; n0 += 4) {
    double d0 = (double)fp[(size_t)(n0 + 0) << 8];
    double d1 = (double)fp[(size_t)(n0 + 1) << 8];
    double d2 = (double)fp[(size_t)(n0 + 2) << 8];
    double d3 = (double)fp[(size_t)(n0 + 3) << 8];
#pragma unroll
    for (int c = 0; c < 20; ++c) {
      const double* av = &adjs[c][n0];
      t[c] += av[0] * d0 + av[1] * d1 + av[2] * d2 + av[3] * d3;
    }
  }
  double* pxb = px + ((size_t)(b * 4 + ch) * 20) * 256 + tid;
#pragma unroll
  for (int c = 0; c < 20; ++c) pxb[(size_t)c * 256] = t[c];
}

// ---------------------------------------------------------------------------
__device__ __forceinline__ float brs(float v) {
  __shared__ float sb[4];
#pragma unroll
  for (int off = 32; off >= 1; off >>= 1) v += __shfl_xor(v, off);
  __syncthreads();
  if ((threadIdx.x & 63) == 0) sb[threadIdx.x >> 6] = v;
  __syncthreads();
  return sb[0] + sb[1] + sb[2] + sb[3];
}

// ---------------------------------------------------------------------------
// k3c: one block/batch. Reduce t partials, x = t @ W0 (fp32), exact LN0
// scores per candidate (per-wave parallel), winner per stage, then the tail.
// ---------------------------------------------------------------------------
__global__ __launch_bounds__(256) void k3c_final(
    const double* __restrict__ px, const int* __restrict__ candbuf,
    const float* __restrict__ W0, const float* __restrict__ b0,
    const float* __restrict__ b1, const float* __restrict__ W2,
    const float* __restrict__ b2, const float* __restrict__ g0,
    const float* __restrict__ be0, const float* __restrict__ g1,
    const float* __restrict__ be1, const float* __restrict__ g2,
    const float* __restrict__ be2, const float* __restrict__ fcW,
    const float* __restrict__ fcb, float* __restrict__ out)
{
  __shared__ __align__(16) float tfT[Fn * 20];   // [f][c]
  __shared__ float xb[20][Hn];
  __shared__ float b0s[Hn], g0s[Hn], be0s[Hn];
  __shared__ float cm[20], cr[20], csc[20];
  __shared__ int candL[20], candvL[20], winslot[NSn];
  __shared__ float xs[Hn];
  const int tid = (int)threadIdx.x;
  const int b = blockIdx.x;

  if (tid < 20) {
    candL[tid] = candbuf[b * 40 + tid];
    candvL[tid] = candbuf[b * 40 + 20 + tid];
  }
  b0s[tid] = b0[tid]; g0s[tid] = g0[tid]; be0s[tid] = be0[tid];
  {
    const double* pxb = px + ((size_t)b * 4 * 20) * 256 + tid;
#pragma unroll
    for (int c = 0; c < 20; ++c) {
      double t = pxb[(size_t)c * 256] + pxb[(size_t)(20 + c) * 256] +
                 pxb[(size_t)(40 + c) * 256] + pxb[(size_t)(60 + c) * 256];
      tfT[tid * 20 + c] = (float)t;
    }
  }
  __syncthreads();

  {
    float xc[20];
#pragma unroll
    for (int c = 0; c < 20; ++c) xc[c] = 0.f;
    for (int f = 0; f < Fn; ++f) {
      float w = W0[(size_t)f * Hn + tid];
      const float* tp = &tfT[f * 20];
      float4 t0 = *(const float4*)(tp);
      float4 t1 = *(const float4*)(tp + 4);
      float4 t2 = *(const float4*)(tp + 8);
      float4 t3 = *(const float4*)(tp + 12);
      float4 t4 = *(const float4*)(tp + 16);
      xc[0] = fmaf(t0.x, w, xc[0]);   xc[1] = fmaf(t0.y, w, xc[1]);
      xc[2] = fmaf(t0.z, w, xc[2]);   xc[3] = fmaf(t0.w, w, xc[3]);
      xc[4] = fmaf(t1.x, w, xc[4]);   xc[5] = fmaf(t1.y, w, xc[5]);
      xc[6] = fmaf(t1.z, w, xc[6]);   xc[7] = fmaf(t1.w, w, xc[7]);
      xc[8] = fmaf(t2.x, w, xc[8]);   xc[9] = fmaf(t2.y, w, xc[9]);
      xc[10] = fmaf(t2.z, w, xc[10]); xc[11] = fmaf(t2.w, w, xc[11]);
      xc[12] = fmaf(t3.x, w, xc[12]); xc[13] = fmaf(t3.y, w, xc[13]);
      xc[14] = fmaf(t3.z, w, xc[14]); xc[15] = fmaf(t3.w, w, xc[15]);
      xc[16] = fmaf(t4.x, w, xc[16]); xc[17] = fmaf(t4.y, w, xc[17]);
      xc[18] = fmaf(t4.z, w, xc[18]); xc[19] = fmaf(t4.w, w, xc[19]);
    }
#pragma unroll
    for (int c = 0; c < 20; ++c) xb[c][tid] = xc[c];
  }
  __syncthreads();

  {
    const int wv = tid >> 6, lane = tid & 63;
    for (int c = wv; c < 20; c += 4) {
      float v0 = xb[c][lane] + b0s[lane];
      float v1 = xb[c][lane + 64] + b0s[lane + 64];
      float v2 = xb[c][lane + 128] + b0s[lane + 128];
      float v3 = xb[c][lane + 192] + b0s[lane + 192];
      float s = v0 + v1 + v2 + v3;
#pragma unroll
      for (int off = 32; off >= 1; off >>= 1) s += __shfl_xor(s, off);
      float m = s * (1.0f / Hn);
      float d0 = v0 - m, d1 = v1 - m, d2 = v2 - m, d3 = v3 - m;
      float s2 = d0 * d0 + d1 * d1 + d2 * d2 + d3 * d3;
#pragma unroll
      for (int off = 32; off >= 1; off >>= 1) s2 += __shfl_xor(s2, off);
      float rstd = 1.0f / sqrtf(s2 * (1.0f / Hn) + EPS);
      float sc = fmaxf(d0 * rstd * g0s[lane] + be0s[lane], 0.f) +
                 fmaxf(d1 * rstd * g0s[lane + 64] + be0s[lane + 64], 0.f) +
                 fmaxf(d2 * rstd * g0s[lane + 128] + be0s[lane + 128], 0.f) +
                 fmaxf(d3 * rstd * g0s[lane + 192] + be0s[lane + 192], 0.f);
#pragma unroll
      for (int off = 32; off >= 1; off >>= 1) sc += __shfl_xor(sc, off);
      if (lane == 0) { cm[c] = m; cr[c] = rstd; csc[c] = sc; }
    }
  }
  __syncthreads();

  if (tid == 0) {
#pragma unroll
    for (int s = 0; s < NSn; ++s) {
      int wsl = s * 4;
      float bestv = 0.f; int bestn = 0; bool any = false;
      for (int j = 0; j < 4; ++j) {
        int c = s * 4 + j;
        if (!candvL[c]) continue;
        float v = csc[c]; int node = candL[c];
        if (!any || v > bestv || (v == bestv && node < bestn)) {
          any = true; bestv = v; bestn = node; wsl = c;
        }
      }
      winslot[s] = wsl;
    }
  }
  __syncthreads();

  const float b0t = b0s[tid], g0t = g0s[tid], be0t = be0s[tid];
  const float b1t = b1[tid], g1t = g1[tid], be1t = be1[tid];
  float xsum = 0.f;
  for (int s = 0; s < NSn; ++s) {
    int c = winslot[s];
    float xv = xb[c][tid] + b0t;
    float z0 = (xv - cm[c]) * cr[c] * g0t + be0t;
    float o = fmaxf(z0, 0.f) + b1t;
    float m1 = brs(o) * (1.0f / Hn);
    float d1 = o - m1;
    float v1 = brs(d1 * d1) * (1.0f / Hn);
    float z1 = d1 * (1.0f / sqrtf(v1 + EPS)) * g1t + be1t;
    xsum += fmaxf(z1, 0.f);
  }
  xs[tid] = xsum;
  __syncthreads();
  float y = 0.f;
  for (int h = 0; h < Hn; h += 4) {
    float4 xv4 = *(const float4*)&xs[h];
    y = fmaf(xv4.x, W2[(size_t)h * Hn + tid], y);
    y = fmaf(xv4.y, W2[(size_t)(h + 1) * Hn + tid], y);
    y = fmaf(xv4.z, W2[(size_t)(h + 2) * Hn + tid], y);
    y = fmaf(xv4.w, W2[(size_t)(h + 3) * Hn + tid], y);
  }
  y += b2[tid];
  float m2 = brs(y) * (1.0f / Hn);
  float d2 = y - m2;
  float v2 = brs(d2 * d2) * (1.0f / Hn);
  float z2 = d2 * (1.0f / sqrtf(v2 + EPS)) * g2[tid] + be2[tid];
  float p = fmaxf(z2, 0.f) * fcW[tid];
  float tot = brs(p);
  if (tid == 0) out[b] = tot + fcb[0];
}

// ---------------------------------------------------------------------------
extern "C" void kernel_launch(void* const* d_in, const int* in_sizes, int n_in,
                              void* d_out, int out_size, void* d_ws, size_t ws_size,
                              hipStream_t stream)
{
  (void)in_sizes; (void)n_in; (void)out_size; (void)ws_size;
  const float* adj  = (const float*)d_in[0];
  const float* feat = (const float*)d_in[1];
  const int*   sid  = (const int*)d_in[2];
  const float* W0   = (const float*)d_in[3];
  const float* b0   = (const float*)d_in[4];
  const float* b1   = (const float*)d_in[5];
  const float* W2   = (const float*)d_in[6];
  const float* b2   = (const float*)d_in[7];
  const float* g0   = (const float*)d_in[8];
  const float* be0  = (const float*)d_in[9];
  const float* g1   = (const float*)d_in[10];
  const float* be1  = (const float*)d_in[11];
  const float* g2   = (const float*)d_in[12];
  const float* be2  = (const float*)d_in[13];
  const float* fcW  = (const float*)d_in[14];
  const float* fcb  = (const float*)d_in[15];
  float* out = (float*)d_out;

  // ws: supT bf16 [B][H][N] 67,108,864 | W0T bf16 131,072 | scores f32 524,288
  //     | candbuf int 40,960 | px f64 41,943,040
  unsigned short* supT = (unsigned short*)d_ws;
  unsigned short* W0T  = (unsigned short*)((char*)d_ws + 67108864);
  float* scores        = (float*)((char*)d_ws + 67239936);
  int* candbuf         = (int*)((char*)d_ws + 67764224);
  double* px           = (double*)((char*)d_ws + 67805184);

  k0_prep<<<dim3(16), dim3(256), 0, stream>>>(W0, W0T);
  k1_support<<<dim3(1024), dim3(512), 0, stream>>>(feat, W0T, supT);
  k2_scores<<<dim3(1024), dim3(512), 0, stream>>>(adj, supT, b0, g0, be0, scores);
  k3a_select<<<dim3(256), dim3(256), 0, stream>>>(scores, sid, candbuf);
  k3b_part<<<dim3(1024), dim3(256), 0, stream>>>(adj, feat, candbuf, px);
  k3c_final<<<dim3(256), dim3(256), 0, stream>>>(px, candbuf,
      W0, b0, b1, W2, b2, g0, be0, g1, be1, g2, be2, fcW, fcb, out);
}